// Round 1
// baseline (669.845 us; speedup 1.0000x reference)
//
#include <hip/hip_runtime.h>

typedef unsigned short ushort_t;
using bf16x8 = __attribute__((ext_vector_type(8))) short;
using u16x8  = __attribute__((ext_vector_type(8))) unsigned short;
using f32x4  = __attribute__((ext_vector_type(4))) float;

#define DEV static __device__ __forceinline__

DEV unsigned short f2bf(float f) {
  union { float f; unsigned u; } a; a.f = f;
  unsigned r = a.u + 0x7fffu + ((a.u >> 16) & 1u);
  return (unsigned short)(r >> 16);
}
DEV float bf2f(unsigned short u) {
  union { unsigned u; float f; } a; a.u = ((unsigned)u) << 16;
  return a.f;
}
DEV void load_lds16(const void* g, void* l) {
  __builtin_amdgcn_global_load_lds(
      (const __attribute__((address_space(1))) void*)g,
      (__attribute__((address_space(3))) void*)l, 16, 0, 0);
}

// ---------------------------------------------------------------- casts
__global__ __launch_bounds__(256) void cast_kernel(
    const float* __restrict__ src, ushort_t* __restrict__ dst, int n4) {
  int i = blockIdx.x * 256 + threadIdx.x;
  if (i >= n4) return;
  float4 f = ((const float4*)src)[i];
  ushort4 o;
  o.x = f2bf(f.x); o.y = f2bf(f.y); o.z = f2bf(f.z); o.w = f2bf(f.w);
  ((ushort4*)dst)[i] = o;
}

// ---------------------------------------------------------------- rope tables
__global__ __launch_bounds__(256) void rope_tables_kernel(float* __restrict__ tab) {
  int idx = blockIdx.x * 256 + threadIdx.x;   // < 2048*64
  int s = idx >> 6, i = idx & 63;
  // 10000^(-2i/128) = 2^(-log2(10000)*2i/128)
  float rate = exp2f(-13.287712379549449f * ((float)(2 * i) * (1.0f / 128.0f)));
  float ang = (float)s * rate;
  tab[idx * 2]     = cosf(ang);
  tab[idx * 2 + 1] = sinf(ang);
}

// ---------------------------------------------------------------- GEMM  C = A * B^T
// A[M][K], B[N][K] bf16 row-major; C fp32 or bf16. 128x128 tile, BK=32, m97 structure.
template<int OUTF32>
__global__ __launch_bounds__(256) void gemm_bt(
    const ushort_t* __restrict__ A, const ushort_t* __restrict__ B,
    void* __restrict__ C, int M, int N, int K) {
  __shared__ __align__(16) ushort_t sA[128 * 32];
  __shared__ __align__(16) ushort_t sB[128 * 32];
  const int tid  = threadIdx.x;
  const int wave = tid >> 6;
  const int lane = tid & 63;
  const int lrow = lane & 15;
  const int lk   = lane >> 4;
  const int bm = blockIdx.y * 128;
  const int bn = blockIdx.x * 128;
  const int wrow = (wave >> 1) * 64;
  const int wcol = (wave & 1) * 64;

  f32x4 acc[4][4];
#pragma unroll
  for (int r = 0; r < 4; ++r)
#pragma unroll
    for (int c = 0; c < 4; ++c) acc[r][c] = (f32x4){0.f, 0.f, 0.f, 0.f};

  // staging: 8 chunks of 1KB per matrix; wave handles chunks {2w, 2w+1}
  // LDS linear (gload_lds), source pre-swizzled: byte_in_row ^= (row&3)<<4
  const int sRow0 = wave * 32 + (lane >> 2);
  const int sRow1 = sRow0 + 16;
  const int sSwz  = ((lane & 3) * 16) ^ ((sRow0 & 3) << 4);
  const char* aS0 = (const char*)A + (size_t)(bm + sRow0) * (size_t)(K * 2) + sSwz;
  const char* aS1 = (const char*)A + (size_t)(bm + sRow1) * (size_t)(K * 2) + sSwz;
  const char* bS0 = (const char*)B + (size_t)(bn + sRow0) * (size_t)(K * 2) + sSwz;
  const char* bS1 = (const char*)B + (size_t)(bn + sRow1) * (size_t)(K * 2) + sSwz;
  char* aD0 = (char*)sA + wave * 2048 + lane * 16;
  char* aD1 = aD0 + 1024;
  char* bD0 = (char*)sB + wave * 2048 + lane * 16;
  char* bD1 = bD0 + 1024;

  int offA[4], offB[4];
  const int fSwz = (lk * 16) ^ ((lrow & 3) << 4);
#pragma unroll
  for (int r = 0; r < 4; ++r) offA[r] = (wrow + r * 16 + lrow) * 64 + fSwz;
#pragma unroll
  for (int c = 0; c < 4; ++c) offB[c] = (wcol + c * 16 + lrow) * 64 + fSwz;

  const int nk = K >> 5;
  for (int ks = 0; ks < nk; ++ks) {
    const size_t koff = (size_t)ks * 64;
    load_lds16(aS0 + koff, aD0);
    load_lds16(aS1 + koff, aD1);
    load_lds16(bS0 + koff, bD0);
    load_lds16(bS1 + koff, bD1);
    __syncthreads();
    bf16x8 af[4], bv[4];
#pragma unroll
    for (int r = 0; r < 4; ++r) af[r] = *(const bf16x8*)((const char*)sA + offA[r]);
#pragma unroll
    for (int c = 0; c < 4; ++c) bv[c] = *(const bf16x8*)((const char*)sB + offB[c]);
#pragma unroll
    for (int r = 0; r < 4; ++r)
#pragma unroll
      for (int c = 0; c < 4; ++c)
        acc[r][c] = __builtin_amdgcn_mfma_f32_16x16x32_bf16(af[r], bv[c], acc[r][c], 0, 0, 0);
    __syncthreads();
  }

#pragma unroll
  for (int r = 0; r < 4; ++r)
#pragma unroll
    for (int i = 0; i < 4; ++i) {
      const size_t row = (size_t)(bm + wrow + r * 16 + lk * 4 + i);
#pragma unroll
      for (int c = 0; c < 4; ++c) {
        const size_t col = (size_t)(bn + wcol + c * 16 + lrow);
        float v = acc[r][c][i];
        if (OUTF32) ((float*)C)[row * (size_t)N + col] = v;
        else        ((ushort_t*)C)[row * (size_t)N + col] = f2bf(v);
      }
    }
}

// ---------------------------------------------------------------- RoPE + RMS + relayout
// qkv (B,S,3E) bf16 -> q,k,v (B,H,S,D) bf16; rope+rms on q,k; 1/sqrt(D) folded into q.
__global__ __launch_bounds__(256) void rope_rms_kernel(
    const ushort_t* __restrict__ qkv, ushort_t* __restrict__ q,
    ushort_t* __restrict__ k, ushort_t* __restrict__ v,
    const float* __restrict__ tab) {
  const int lane = threadIdx.x & 63;
  const int row  = blockIdx.x * 4 + (threadIdx.x >> 6);  // (((b*S+s)*3)+which)*16+h
  const int h = row & 15;
  int t = row >> 4;
  const int which = t % 3; t /= 3;
  const int s = t & 2047;
  const int b = t >> 11;
  const size_t src = ((size_t)(b * 2048 + s)) * 6144 + which * 2048 + h * 128 + lane * 2;
  ushort2 xv = *(const ushort2*)&qkv[src];
  float lo = bf2f(xv.x), ro = bf2f(xv.y);
  if (which < 2) {
    const float2 cs = *(const float2*)&tab[(s * 64 + lane) * 2];
    float l2 = lo * cs.x - ro * cs.y;
    float r2 = lo * cs.y + ro * cs.x;
    float ss = l2 * l2 + r2 * r2;
#pragma unroll
    for (int off = 1; off < 64; off <<= 1) ss += __shfl_xor(ss, off);
    float inv = rsqrtf(ss * (1.0f / 128.0f) + 1.1920928955078125e-07f);
    if (which == 0) inv *= 0.08838834764831845f;  // 1/sqrt(128)
    lo = l2 * inv; ro = r2 * inv;
  }
  ushort_t* dst = (which == 0) ? q : ((which == 1) ? k : v);
  ushort2 o; o.x = f2bf(lo); o.y = f2bf(ro);
  *(ushort2*)&dst[(((size_t)(b * 16 + h)) * 2048 + s) * 128 + lane * 2] = o;
}

// ---------------------------------------------------------------- flash attention (causal)
// grid (32 qtiles, 32 bh); 4 waves x 16 q-rows; KBLK=32; online softmax.
// Y written in (B,S,E) layout, bf16.
__global__ __launch_bounds__(256) void attn_kernel(
    const ushort_t* __restrict__ Q, const ushort_t* __restrict__ K,
    const ushort_t* __restrict__ V, ushort_t* __restrict__ Y) {
  __shared__ __align__(16) ushort_t sK[32 * 128];   // swizzled: byte^=((row&7)<<4)
  __shared__ __align__(16) ushort_t sVt[128 * 40];  // V^T, padded rows (80B)
  __shared__ __align__(16) ushort_t sP[4 * 16 * 40];
  const int qt = 31 - (int)blockIdx.x;   // long blocks first
  const int bh = blockIdx.y;
  const int wave = threadIdx.x >> 6, lane = threadIdx.x & 63;
  const int lrow = lane & 15, lk = lane >> 4;
  const size_t hbase = (size_t)bh * 2048 * 128;
  const int q0 = qt * 64 + wave * 16;

  bf16x8 qf[4];
#pragma unroll
  for (int dc = 0; dc < 4; ++dc)
    qf[dc] = *(const bf16x8*)&Q[hbase + (size_t)(q0 + lrow) * 128 + dc * 32 + lk * 8];

  f32x4 acc[8];
#pragma unroll
  for (int g = 0; g < 8; ++g) acc[g] = (f32x4){0.f, 0.f, 0.f, 0.f};
  float mrow[4], lsum[4];
#pragma unroll
  for (int i = 0; i < 4; ++i) { mrow[i] = -__builtin_inff(); lsum[i] = 0.f; }

  ushort_t* sPw = sP + wave * 16 * 40;
  const int ktiles = qt * 2 + 2;
  for (int kt = 0; kt < ktiles; ++kt) {
    const char* kb = (const char*)(K + hbase + (size_t)kt * 32 * 128);
    const char* vb = (const char*)(V + hbase + (size_t)kt * 32 * 128);
    // stage K tile via gload_lds, source pre-swizzled
#pragma unroll
    for (int half = 0; half < 2; ++half) {
      int c = wave * 2 + half;
      int row = c * 4 + lk;
      int srcoff = row * 256 + (((lane & 15) * 16) ^ ((row & 7) << 4));
      load_lds16(kb + srcoff, (char*)sK + c * 1024 + lane * 16);
    }
    // stage V^T (reg load + scalar transposed writes, padded stride 40)
#pragma unroll
    for (int half = 0; half < 2; ++half) {
      int c = (int)threadIdx.x + half * 256;  // 0..511
      int key = c >> 4;
      int d0 = (c & 15) * 8;
      u16x8 vv = *(const u16x8*)(vb + ((size_t)key * 128 + d0) * 2);
#pragma unroll
      for (int j = 0; j < 8; ++j) sVt[(d0 + j) * 40 + key] = (ushort_t)vv[j];
    }
    __syncthreads();

    if (kt * 32 <= q0 + 15) {
      // S = Q * K^T  (scale pre-folded into q)
      f32x4 s[2];
      s[0] = (f32x4){0.f, 0.f, 0.f, 0.f};
      s[1] = (f32x4){0.f, 0.f, 0.f, 0.f};
#pragma unroll
      for (int g = 0; g < 2; ++g) {
        const int row = g * 16 + lrow;
#pragma unroll
        for (int dc = 0; dc < 4; ++dc) {
          int off = row * 256 + ((dc * 64 + lk * 16) ^ ((row & 7) << 4));
          bf16x8 kf = *(const bf16x8*)((const char*)sK + off);
          s[g] = __builtin_amdgcn_mfma_f32_16x16x32_bf16(qf[dc], kf, s[g], 0, 0, 0);
        }
      }
      // causal mask
      float sv[2][4];
#pragma unroll
      for (int g = 0; g < 2; ++g)
#pragma unroll
        for (int i = 0; i < 4; ++i) {
          int key = kt * 32 + g * 16 + lrow;
          int qa  = q0 + lk * 4 + i;
          sv[g][i] = (key <= qa) ? s[g][i] : -1e30f;
        }
      // online softmax
      float mt[4];
#pragma unroll
      for (int i = 0; i < 4; ++i) mt[i] = fmaxf(sv[0][i], sv[1][i]);
#pragma unroll
      for (int off = 1; off < 16; off <<= 1)
#pragma unroll
        for (int i = 0; i < 4; ++i) mt[i] = fmaxf(mt[i], __shfl_xor(mt[i], off));
      float pg[2][4], rs[4], corr[4];
#pragma unroll
      for (int i = 0; i < 4; ++i) {
        float mn = fmaxf(mrow[i], mt[i]);
        corr[i] = __expf(mrow[i] - mn);
        mrow[i] = mn;
        pg[0][i] = __expf(sv[0][i] - mn);
        pg[1][i] = __expf(sv[1][i] - mn);
        rs[i] = pg[0][i] + pg[1][i];
      }
#pragma unroll
      for (int off = 1; off < 16; off <<= 1)
#pragma unroll
        for (int i = 0; i < 4; ++i) rs[i] += __shfl_xor(rs[i], off);
#pragma unroll
      for (int i = 0; i < 4; ++i) lsum[i] = lsum[i] * corr[i] + rs[i];
#pragma unroll
      for (int g = 0; g < 8; ++g)
#pragma unroll
        for (int i = 0; i < 4; ++i) acc[g][i] *= corr[i];
      // P -> LDS (bf16)
#pragma unroll
      for (int g = 0; g < 2; ++g)
#pragma unroll
        for (int i = 0; i < 4; ++i)
          sPw[(lk * 4 + i) * 40 + g * 16 + lrow] = f2bf(pg[g][i]);
      asm volatile("s_waitcnt lgkmcnt(0)" ::: "memory");
      // PV
      bf16x8 pa = *(const bf16x8*)&sPw[lrow * 40 + lk * 8];
#pragma unroll
      for (int cg = 0; cg < 8; ++cg) {
        bf16x8 vf = *(const bf16x8*)&sVt[(cg * 16 + lrow) * 40 + lk * 8];
        acc[cg] = __builtin_amdgcn_mfma_f32_16x16x32_bf16(pa, vf, acc[cg], 0, 0, 0);
      }
    }
    __syncthreads();
  }

  // epilogue: Y (B,S,E) bf16
  const int b = bh >> 4, h = bh & 15;
#pragma unroll
  for (int i = 0; i < 4; ++i) {
    float inv = 1.f / lsum[i];
    int qrow = q0 + lk * 4 + i;
    size_t orow = ((size_t)(b * 2048 + qrow)) * 2048 + h * 128;
#pragma unroll
    for (int cg = 0; cg < 8; ++cg)
      Y[orow + cg * 16 + lrow] = f2bf(acc[cg][i] * inv);
  }
}

// ---------------------------------------------------------------- launch
extern "C" void kernel_launch(void* const* d_in, const int* in_sizes, int n_in,
                              void* d_out, int out_size, void* d_ws, size_t ws_size,
                              hipStream_t stream) {
  const float* x     = (const float*)d_in[0];
  const float* wqkv  = (const float*)d_in[1];
  const float* wproj = (const float*)d_in[2];
  float* out = (float*)d_out;
  char* ws = (char*)d_ws;

  // workspace layout (bytes)
  ushort_t* x_bf     = (ushort_t*)(ws);                // 16,777,216
  ushort_t* wqkv_bf  = (ushort_t*)(ws + 16777216);     // 25,165,824
  ushort_t* wproj_bf = (ushort_t*)(ws + 41943040);     //  8,388,608
  ushort_t* qkv_bf   = (ushort_t*)(ws + 50331648);     // 50,331,648 (reused as y)
  ushort_t* q_bf     = (ushort_t*)(ws + 100663296);    // 16,777,216
  ushort_t* k_bf     = (ushort_t*)(ws + 117440512);    // 16,777,216
  ushort_t* v_bf     = (ushort_t*)(ws + 134217728);    // 16,777,216
  float*    tab      = (float*)(ws + 150994944);       //  1,048,576
  if (ws_size < 152043520u) return;                    // need ~145 MB

  cast_kernel<<<8192, 256, 0, stream>>>(x, x_bf, 2097152);
  cast_kernel<<<12288, 256, 0, stream>>>(wqkv, wqkv_bf, 3145728);
  cast_kernel<<<4096, 256, 0, stream>>>(wproj, wproj_bf, 1048576);
  rope_tables_kernel<<<512, 256, 0, stream>>>(tab);

  // qkv = x @ w_qkv^T   (4096 x 6144 x 2048), bf16 out
  gemm_bt<0><<<dim3(48, 32), 256, 0, stream>>>(x_bf, wqkv_bf, qkv_bf, 4096, 6144, 2048);

  rope_rms_kernel<<<49152, 256, 0, stream>>>(qkv_bf, q_bf, k_bf, v_bf, tab);

  attn_kernel<<<dim3(32, 32), 256, 0, stream>>>(q_bf, k_bf, v_bf, qkv_bf /* y */);

  // out = y @ w_proj^T  (4096 x 2048 x 2048), fp32 out
  gemm_bt<1><<<dim3(16, 32), 256, 0, stream>>>(qkv_bf, wproj_bf, out, 4096, 2048, 2048);
}

// Round 2
// 344.724 us; speedup vs baseline: 1.9431x; 1.9431x over previous
//
#include <hip/hip_runtime.h>

typedef unsigned short ushort_t;
using bf16x8 = __attribute__((ext_vector_type(8))) short;
using u16x8  = __attribute__((ext_vector_type(8))) unsigned short;
using f32x4  = __attribute__((ext_vector_type(4))) float;

#define DEV static __device__ __forceinline__

DEV unsigned short f2bf(float f) {
  union { float f; unsigned u; } a; a.f = f;
  unsigned r = a.u + 0x7fffu + ((a.u >> 16) & 1u);
  return (unsigned short)(r >> 16);
}
DEV float bf2f(unsigned short u) {
  union { unsigned u; float f; } a; a.u = ((unsigned)u) << 16;
  return a.f;
}
DEV void load_lds16(const void* g, void* l) {
  __builtin_amdgcn_global_load_lds(
      (const __attribute__((address_space(1))) void*)g,
      (__attribute__((address_space(3))) void*)l, 16, 0, 0);
}

// ---------------------------------------------------------------- casts
__global__ __launch_bounds__(256) void cast_kernel(
    const float* __restrict__ src, ushort_t* __restrict__ dst, int n4) {
  int i = blockIdx.x * 256 + threadIdx.x;
  if (i >= n4) return;
  float4 f = ((const float4*)src)[i];
  ushort4 o;
  o.x = f2bf(f.x); o.y = f2bf(f.y); o.z = f2bf(f.z); o.w = f2bf(f.w);
  ((ushort4*)dst)[i] = o;
}

// ---------------------------------------------------------------- rope tables
__global__ __launch_bounds__(256) void rope_tables_kernel(float* __restrict__ tab) {
  int idx = blockIdx.x * 256 + threadIdx.x;   // < 2048*64
  int s = idx >> 6, i = idx & 63;
  float rate = exp2f(-13.287712379549449f * ((float)(2 * i) * (1.0f / 128.0f)));
  float ang = (float)s * rate;
  tab[idx * 2]     = cosf(ang);
  tab[idx * 2 + 1] = sinf(ang);
}

// ---------------------------------------------------------------- GEMM  C = A * B^T
template<int OUTF32>
__global__ __launch_bounds__(256) void gemm_bt(
    const ushort_t* __restrict__ A, const ushort_t* __restrict__ B,
    void* __restrict__ C, int M, int N, int K) {
  __shared__ __align__(16) ushort_t sA[128 * 32];
  __shared__ __align__(16) ushort_t sB[128 * 32];
  const int tid  = threadIdx.x;
  const int wave = tid >> 6;
  const int lane = tid & 63;
  const int lrow = lane & 15;
  const int lk   = lane >> 4;
  const int bm = blockIdx.y * 128;
  const int bn = blockIdx.x * 128;
  const int wrow = (wave >> 1) * 64;
  const int wcol = (wave & 1) * 64;

  f32x4 acc[4][4];
#pragma unroll
  for (int r = 0; r < 4; ++r)
#pragma unroll
    for (int c = 0; c < 4; ++c) acc[r][c] = (f32x4){0.f, 0.f, 0.f, 0.f};

  const int sRow0 = wave * 32 + (lane >> 2);
  const int sRow1 = sRow0 + 16;
  const int sSwz  = ((lane & 3) * 16) ^ ((sRow0 & 3) << 4);
  const char* aS0 = (const char*)A + (size_t)(bm + sRow0) * (size_t)(K * 2) + sSwz;
  const char* aS1 = (const char*)A + (size_t)(bm + sRow1) * (size_t)(K * 2) + sSwz;
  const char* bS0 = (const char*)B + (size_t)(bn + sRow0) * (size_t)(K * 2) + sSwz;
  const char* bS1 = (const char*)B + (size_t)(bn + sRow1) * (size_t)(K * 2) + sSwz;
  char* aD0 = (char*)sA + wave * 2048 + lane * 16;
  char* aD1 = aD0 + 1024;
  char* bD0 = (char*)sB + wave * 2048 + lane * 16;
  char* bD1 = bD0 + 1024;

  int offA[4], offB[4];
  const int fSwz = (lk * 16) ^ ((lrow & 3) << 4);
#pragma unroll
  for (int r = 0; r < 4; ++r) offA[r] = (wrow + r * 16 + lrow) * 64 + fSwz;
#pragma unroll
  for (int c = 0; c < 4; ++c) offB[c] = (wcol + c * 16 + lrow) * 64 + fSwz;

  const int nk = K >> 5;
  for (int ks = 0; ks < nk; ++ks) {
    const size_t koff = (size_t)ks * 64;
    load_lds16(aS0 + koff, aD0);
    load_lds16(aS1 + koff, aD1);
    load_lds16(bS0 + koff, bD0);
    load_lds16(bS1 + koff, bD1);
    __syncthreads();
    bf16x8 af[4], bv[4];
#pragma unroll
    for (int r = 0; r < 4; ++r) af[r] = *(const bf16x8*)((const char*)sA + offA[r]);
#pragma unroll
    for (int c = 0; c < 4; ++c) bv[c] = *(const bf16x8*)((const char*)sB + offB[c]);
#pragma unroll
    for (int r = 0; r < 4; ++r)
#pragma unroll
      for (int c = 0; c < 4; ++c)
        acc[r][c] = __builtin_amdgcn_mfma_f32_16x16x32_bf16(af[r], bv[c], acc[r][c], 0, 0, 0);
    __syncthreads();
  }

#pragma unroll
  for (int r = 0; r < 4; ++r)
#pragma unroll
    for (int i = 0; i < 4; ++i) {
      const size_t row = (size_t)(bm + wrow + r * 16 + lk * 4 + i);
#pragma unroll
      for (int c = 0; c < 4; ++c) {
        const size_t col = (size_t)(bn + wcol + c * 16 + lrow);
        float v = acc[r][c][i];
        if (OUTF32) ((float*)C)[row * (size_t)N + col] = v;
        else        ((ushort_t*)C)[row * (size_t)N + col] = f2bf(v);
      }
    }
}

// ---------------------------------------------------------------- RoPE + RMS + relayout
// qkv (B,S,3E) bf16 -> q,k (B,H,S,D) bf16 (rope+rms, scale*log2e folded into q);
// v -> vt (B,H,D,S) bf16 (transposed scatter, no transform).
__global__ __launch_bounds__(256) void rope_rms_kernel(
    const ushort_t* __restrict__ qkv, ushort_t* __restrict__ q,
    ushort_t* __restrict__ k, ushort_t* __restrict__ vt,
    const float* __restrict__ tab) {
  const int lane = threadIdx.x & 63;
  const int row  = blockIdx.x * 4 + (threadIdx.x >> 6);  // (((b*S+s)*3)+which)*16+h
  const int h = row & 15;
  int t = row >> 4;
  const int which = t % 3; t /= 3;
  const int s = t & 2047;
  const int b = t >> 11;
  const size_t src = ((size_t)(b * 2048 + s)) * 6144 + which * 2048 + h * 128 + lane * 2;
  ushort2 xv = *(const ushort2*)&qkv[src];
  if (which == 2) {
    size_t vbase = ((size_t)((b * 16 + h) * 128 + lane * 2)) * 2048 + s;
    vt[vbase]        = xv.x;
    vt[vbase + 2048] = xv.y;
    return;
  }
  float lo = bf2f(xv.x), ro = bf2f(xv.y);
  const float2 cs = *(const float2*)&tab[(s * 64 + lane) * 2];
  float l2 = lo * cs.x - ro * cs.y;
  float r2 = lo * cs.y + ro * cs.x;
  float ss = l2 * l2 + r2 * r2;
#pragma unroll
  for (int off = 1; off < 64; off <<= 1) ss += __shfl_xor(ss, off);
  float inv = rsqrtf(ss * (1.0f / 128.0f) + 1.1920928955078125e-07f);
  if (which == 0) inv *= 0.1275174398f;  // (1/sqrt(128)) * log2(e)
  lo = l2 * inv; ro = r2 * inv;
  ushort_t* dst = (which == 0) ? q : k;
  ushort2 o; o.x = f2bf(lo); o.y = f2bf(ro);
  *(ushort2*)&dst[(((size_t)(b * 16 + h)) * 2048 + s) * 128 + lane * 2] = o;
}

// ---------------------------------------------------------------- flash attention (causal)
// grid (bh=32, ypair=16). Block = 4 waves; per pass QBLK=64 (wave owns 16 q-rows via
// swapped QK^T: lane&15 = q-row). KBLK=64. Pass 0: qt=yp, pass 1: qt=31-yp (balanced).
// K staged row-permuted (rho) so P^T lands in PV B-frag slots with zero shuffles.
// V^T staged linear from (B,H,D,S) global; XOR swizzle on both source and read.
__global__ __launch_bounds__(256) void attn_kernel(
    const ushort_t* __restrict__ Q, const ushort_t* __restrict__ K,
    const ushort_t* __restrict__ VT, ushort_t* __restrict__ Y) {
  __shared__ __align__(16) ushort_t sK[64 * 128];
  __shared__ __align__(16) ushort_t sV[128 * 64];
  const int bh = blockIdx.x;
  const int yp = blockIdx.y;
  const int wave = threadIdx.x >> 6, lane = threadIdx.x & 63;
  const int ql = lane & 15, lk = lane >> 4;
  const size_t hq = (size_t)bh * 2048 * 128;
  const int b = bh >> 4, h = bh & 15;

  // staging pointers (per thread, hoisted)
  const char* kB = (const char*)(K + hq);
  const char* vB = (const char*)(VT + hq);
  const char* kSrc[4]; char* kDst[4];
  const char* vSrc[4]; char* vDst[4];
#pragma unroll
  for (int t = 0; t < 4; ++t) {
    int r = wave * 16 + t * 4 + (lane >> 4);
    int kgr = r >> 4, lkr = (r >> 2) & 3, ir = r & 3;
    int rho = (kgr >> 1) * 32 + lkr * 8 + (kgr & 1) * 4 + ir;   // key-permutation
    kSrc[t] = kB + rho * 256 + (((lane & 15) * 16) ^ ((r & 7) << 4));
    kDst[t] = (char*)sK + (wave * 256 + t * 64 + lane) * 16;
    int d = wave * 32 + t * 8 + (lane >> 3);
    vSrc[t] = vB + (size_t)d * 4096 + (((lane & 7) * 16) ^ ((d & 7) << 4));
    vDst[t] = (char*)sV + (wave * 256 + t * 64 + lane) * 16;
  }

  for (int pass = 0; pass < 2; ++pass) {
    const int qt = pass ? (31 - yp) : yp;
    const int q = qt * 64 + wave * 16 + ql;

    bf16x8 qf[4];
#pragma unroll
    for (int ks = 0; ks < 4; ++ks)
      qf[ks] = *(const bf16x8*)&Q[hq + (size_t)q * 128 + ks * 32 + lk * 8];

    f32x4 acc[8];
#pragma unroll
    for (int g = 0; g < 8; ++g) acc[g] = (f32x4){0.f, 0.f, 0.f, 0.f};
    float mrow = -3.0e38f, lsum = 0.f;

    for (int kt = 0; kt <= qt; ++kt) {
#pragma unroll
      for (int t = 0; t < 4; ++t) {
        load_lds16(kSrc[t] + (size_t)kt * 16384, kDst[t]);
        load_lds16(vSrc[t] + kt * 128, vDst[t]);
      }
      __syncthreads();

      // S^T = K . Q^T   (lane&15 = q-row; keys permuted by rho)
      f32x4 st[4];
#pragma unroll
      for (int kg = 0; kg < 4; ++kg) st[kg] = (f32x4){0.f, 0.f, 0.f, 0.f};
#pragma unroll
      for (int kg = 0; kg < 4; ++kg) {
        const int row = kg * 16 + ql;
        const int rswz = (row & 7) << 4;
#pragma unroll
        for (int ks = 0; ks < 4; ++ks) {
          bf16x8 kf = *(const bf16x8*)((const char*)sK + row * 256 + ((ks * 64 + lk * 16) ^ rswz));
          st[kg] = __builtin_amdgcn_mfma_f32_16x16x32_bf16(kf, qf[ks], st[kg], 0, 0, 0);
        }
      }
      // causal mask (actual key via rho) + online softmax (base-2)
      float sv[4][4]; float mp = -3.0e38f;
#pragma unroll
      for (int kg = 0; kg < 4; ++kg) {
        const int kl = ((kg >> 1) << 5) + lk * 8 + ((kg & 1) << 2);
#pragma unroll
        for (int i = 0; i < 4; ++i) {
          const int key = kt * 64 + kl + i;
          float v = (key <= q) ? st[kg][i] : -3.0e38f;
          sv[kg][i] = v;
          mp = fmaxf(mp, v);
        }
      }
      mp = fmaxf(mp, __shfl_xor(mp, 16));
      mp = fmaxf(mp, __shfl_xor(mp, 32));
      const float mn = fmaxf(mrow, mp);
      const float corr = exp2f(mrow - mn);
      mrow = mn;
      float p[4][4]; float rs = 0.f;
#pragma unroll
      for (int kg = 0; kg < 4; ++kg)
#pragma unroll
        for (int i = 0; i < 4; ++i) {
          float e = exp2f(sv[kg][i] - mn);
          p[kg][i] = e; rs += e;
        }
      rs += __shfl_xor(rs, 16);
      rs += __shfl_xor(rs, 32);
      lsum = lsum * corr + rs;
#pragma unroll
      for (int g = 0; g < 8; ++g)
#pragma unroll
        for (int i = 0; i < 4; ++i) acc[g][i] *= corr;
      // pack P^T into PV B-frags (own-lane data only, thanks to rho)
      bf16x8 pb[2];
#pragma unroll
      for (int c = 0; c < 2; ++c) {
        union { bf16x8 v; ushort_t u[8]; } pk;
#pragma unroll
        for (int j = 0; j < 8; ++j) pk.u[j] = f2bf(p[2 * c + (j >> 2)][j & 3]);
        pb[c] = pk.v;
      }
      // O^T += V^T . P^T
#pragma unroll
      for (int dg = 0; dg < 8; ++dg) {
        const int d = dg * 16 + ql;
        const int dswz = (d & 7) << 4;
#pragma unroll
        for (int c = 0; c < 2; ++c) {
          bf16x8 vf = *(const bf16x8*)((const char*)sV + d * 128 + ((c * 64 + lk * 16) ^ dswz));
          acc[dg] = __builtin_amdgcn_mfma_f32_16x16x32_bf16(vf, pb[c], acc[dg], 0, 0, 0);
        }
      }
      __syncthreads();
    }

    // epilogue: Y (B,S,E) bf16
    const float inv = 1.0f / lsum;
    const size_t orow = ((size_t)(b * 2048 + q)) * 2048 + h * 128;
#pragma unroll
    for (int dg = 0; dg < 8; ++dg) {
      ushort4 o;
      o.x = f2bf(acc[dg][0] * inv);
      o.y = f2bf(acc[dg][1] * inv);
      o.z = f2bf(acc[dg][2] * inv);
      o.w = f2bf(acc[dg][3] * inv);
      *(ushort4*)&Y[orow + dg * 16 + lk * 4] = o;
    }
  }
}

// ---------------------------------------------------------------- launch
extern "C" void kernel_launch(void* const* d_in, const int* in_sizes, int n_in,
                              void* d_out, int out_size, void* d_ws, size_t ws_size,
                              hipStream_t stream) {
  const float* x     = (const float*)d_in[0];
  const float* wqkv  = (const float*)d_in[1];
  const float* wproj = (const float*)d_in[2];
  float* out = (float*)d_out;
  char* ws = (char*)d_ws;

  ushort_t* x_bf     = (ushort_t*)(ws);                // 16,777,216
  ushort_t* wqkv_bf  = (ushort_t*)(ws + 16777216);     // 25,165,824
  ushort_t* wproj_bf = (ushort_t*)(ws + 41943040);     //  8,388,608
  ushort_t* qkv_bf   = (ushort_t*)(ws + 50331648);     // 50,331,648 (reused as y)
  ushort_t* q_bf     = (ushort_t*)(ws + 100663296);    // 16,777,216
  ushort_t* k_bf     = (ushort_t*)(ws + 117440512);    // 16,777,216
  ushort_t* vt_bf    = (ushort_t*)(ws + 134217728);    // 16,777,216 (B,H,D,S)
  float*    tab      = (float*)(ws + 150994944);       //  1,048,576
  if (ws_size < 152043520u) return;

  cast_kernel<<<8192, 256, 0, stream>>>(x, x_bf, 2097152);
  cast_kernel<<<12288, 256, 0, stream>>>(wqkv, wqkv_bf, 3145728);
  cast_kernel<<<4096, 256, 0, stream>>>(wproj, wproj_bf, 1048576);
  rope_tables_kernel<<<512, 256, 0, stream>>>(tab);

  // qkv = x @ w_qkv^T   (4096 x 6144 x 2048), bf16 out
  gemm_bt<0><<<dim3(48, 32), 256, 0, stream>>>(x_bf, wqkv_bf, qkv_bf, 4096, 6144, 2048);

  rope_rms_kernel<<<49152, 256, 0, stream>>>(qkv_bf, q_bf, k_bf, vt_bf, tab);

  attn_kernel<<<dim3(32, 16), 256, 0, stream>>>(q_bf, k_bf, vt_bf, qkv_bf /* y */);

  // out = y @ w_proj^T  (4096 x 2048 x 2048), fp32 out
  gemm_bt<1><<<dim3(16, 32), 256, 0, stream>>>(qkv_bf, wproj_bf, out, 4096, 2048, 2048);
}

// Round 3
// 317.822 us; speedup vs baseline: 2.1076x; 1.0846x over previous
//
#include <hip/hip_runtime.h>

typedef unsigned short ushort_t;
using bf16x8 = __attribute__((ext_vector_type(8))) short;
using u16x8  = __attribute__((ext_vector_type(8))) unsigned short;
using f32x4  = __attribute__((ext_vector_type(4))) float;

#define DEV static __device__ __forceinline__

DEV unsigned short f2bf(float f) {
  union { float f; unsigned u; } a; a.f = f;
  unsigned r = a.u + 0x7fffu + ((a.u >> 16) & 1u);
  return (unsigned short)(r >> 16);
}
DEV float bf2f(unsigned short u) {
  union { unsigned u; float f; } a; a.u = ((unsigned)u) << 16;
  return a.f;
}
DEV void load_lds16(const void* g, void* l) {
  __builtin_amdgcn_global_load_lds(
      (const __attribute__((address_space(1))) void*)g,
      (__attribute__((address_space(3))) void*)l, 16, 0, 0);
}

// ---------------------------------------------------------------- casts
__global__ __launch_bounds__(256) void cast_kernel(
    const float* __restrict__ src, ushort_t* __restrict__ dst, int n4) {
  int i = blockIdx.x * 256 + threadIdx.x;
  if (i >= n4) return;
  float4 f = ((const float4*)src)[i];
  ushort4 o;
  o.x = f2bf(f.x); o.y = f2bf(f.y); o.z = f2bf(f.z); o.w = f2bf(f.w);
  ((ushort4*)dst)[i] = o;
}

// ---------------------------------------------------------------- rope tables
__global__ __launch_bounds__(256) void rope_tables_kernel(float* __restrict__ tab) {
  int idx = blockIdx.x * 256 + threadIdx.x;   // < 2048*64
  int s = idx >> 6, i = idx & 63;
  float rate = exp2f(-13.287712379549449f * ((float)(2 * i) * (1.0f / 128.0f)));
  float ang = (float)s * rate;
  tab[idx * 2]     = cosf(ang);
  tab[idx * 2 + 1] = sinf(ang);
}

// ---------------------------------------------------------------- deep-pipelined GEMM
// C = A * B^T.  A[M][K], B[N][K] bf16 row-major.  Tile 256 x BN, 512 threads (8 waves,
// wave grid 2M x 4N).  4 LDS slots of BK=32 sub-tiles; counted vmcnt (never 0 in loop).
// Swizzle: 16B-slot XOR ((row>>1)&3) applied on global source + ds_read (LDS linear).
template<int BN, int OUTF32>
__global__ __launch_bounds__(512) void gemm8p(
    const ushort_t* __restrict__ A, const ushort_t* __restrict__ B,
    void* __restrict__ C, int M, int N, int K) {
  constexpr int NF      = BN / 64;          // n-frags per wave (4 or 2)
  constexpr int NSPAN   = BN / 4;           // cols per wave
  constexpr int SLOT_A  = 256 * 32;         // elems
  constexpr int SLOT_B  = BN * 32;
  constexpr int SLOT    = SLOT_A + SLOT_B;  // elems per slot
  constexpr int LOADS_B = BN / 128;         // per-thread B loads (2 or 1)
  constexpr int VMC     = (2 + LOADS_B) * 3;
  __shared__ __align__(16) ushort_t lds[4 * SLOT];

  // bijective chunked XCD swizzle (grid % 8 == 0 by construction)
  const int nby = M >> 8;
  const int nbx = N / BN;
  const int nwg = nby * nbx;
  const int orig = blockIdx.x;
  const int wgid = (orig & 7) * (nwg >> 3) + (orig >> 3);
  const int by = wgid % nby;
  const int bx = wgid / nby;
  const int bm = by * 256, bn = bx * BN;

  const int tid = threadIdx.x;
  const int wave = tid >> 6, lane = tid & 63;
  const int ql = lane & 15, lk = lane >> 4;
  const int wm = wave >> 2, wn = wave & 3;

  f32x4 acc[8][NF];
#pragma unroll
  for (int m = 0; m < 8; ++m)
#pragma unroll
    for (int n = 0; n < NF; ++n) acc[m][n] = (f32x4){0.f, 0.f, 0.f, 0.f};

  // ---- staging geometry (source pre-swizzled, LDS dest linear)
  const int srow = tid >> 2;                              // 0..127
  const int scol = (tid & 3) * 16;                        // byte col in 64B row
  const int sswz = scol ^ (((srow >> 1) & 3) << 4);
  const size_t rbA = (size_t)(K * 2);
  const char* aS0 = (const char*)A + (size_t)(bm + srow) * rbA + sswz;
  const char* aS1 = (const char*)A + (size_t)(bm + srow + 128) * rbA + sswz;
  const char* bS0 = (const char*)B + (size_t)(bn + srow) * rbA + sswz;
  const char* bS1 = (const char*)B + (size_t)(bn + srow + 128) * rbA + sswz;
  char* ldsc = (char*)lds;
  const int dA0 = tid * 16;
  const int dA1 = tid * 16 + 8192;
  const int dB0 = SLOT_A * 2 + tid * 16;
  const int dB1 = SLOT_A * 2 + tid * 16 + 8192;

#define ISSUE(KS, SL) do {                                   \
    const size_t ko = (size_t)(KS) * 64;                     \
    char* sb = ldsc + (SL) * (SLOT * 2);                     \
    load_lds16(aS0 + ko, sb + dA0);                          \
    load_lds16(aS1 + ko, sb + dA1);                          \
    load_lds16(bS0 + ko, sb + dB0);                          \
    if (LOADS_B == 2) load_lds16(bS1 + ko, sb + dB1);        \
  } while (0)

  // ---- fragment read geometry
  const int qswz = ((ql >> 1) & 3) << 4;
  const int fcol = (lk * 16) ^ qswz;
  const int aOff = (wm * 128 + ql) * 64 + fcol;              // bytes within slot
  const int bOff = SLOT_A * 2 + (wn * NSPAN + ql) * 64 + fcol;

  const int ns = K >> 5;
  ISSUE(0, 0); ISSUE(1, 1); ISSUE(2, 2);

  for (int s = 0; s < ns; ++s) {
    int kn = s + 3; if (kn >= ns) kn = ns - 1;   // clamped dummy keeps vmcnt uniform
    ISSUE(kn, (s + 3) & 3);
    if (VMC == 12) asm volatile("s_waitcnt vmcnt(12)" ::: "memory");
    else           asm volatile("s_waitcnt vmcnt(9)"  ::: "memory");
    asm volatile("s_barrier" ::: "memory");

    const char* sb = ldsc + (s & 3) * (SLOT * 2);
    bf16x8 af[8], bfr[NF];
#pragma unroll
    for (int m = 0; m < 8; ++m) af[m] = *(const bf16x8*)(sb + aOff + m * 1024);
#pragma unroll
    for (int n = 0; n < NF; ++n) bfr[n] = *(const bf16x8*)(sb + bOff + n * 1024);

    __builtin_amdgcn_s_setprio(1);
#pragma unroll
    for (int m = 0; m < 8; ++m)
#pragma unroll
      for (int n = 0; n < NF; ++n)
        acc[m][n] = __builtin_amdgcn_mfma_f32_16x16x32_bf16(af[m], bfr[n], acc[m][n], 0, 0, 0);
    __builtin_amdgcn_s_setprio(0);
    asm volatile("s_barrier" ::: "memory");
  }
  asm volatile("s_waitcnt vmcnt(0)" ::: "memory");
#undef ISSUE

#pragma unroll
  for (int m = 0; m < 8; ++m)
#pragma unroll
    for (int i = 0; i < 4; ++i) {
      const size_t row = (size_t)(bm + wm * 128 + m * 16 + lk * 4 + i);
#pragma unroll
      for (int n = 0; n < NF; ++n) {
        const size_t col = (size_t)(bn + wn * NSPAN + n * 16 + ql);
        float v = acc[m][n][i];
        if (OUTF32) ((float*)C)[row * (size_t)N + col] = v;
        else        ((ushort_t*)C)[row * (size_t)N + col] = f2bf(v);
      }
    }
}

// ---------------------------------------------------------------- RoPE + RMS + relayout
// qkv (B,S,3E) bf16 -> q,k (B,H,S,D) bf16 (rope+rms, scale*log2e folded into q);
// v -> vt (B,H,D,S) bf16 (transposed scatter, no transform).
__global__ __launch_bounds__(256) void rope_rms_kernel(
    const ushort_t* __restrict__ qkv, ushort_t* __restrict__ q,
    ushort_t* __restrict__ k, ushort_t* __restrict__ vt,
    const float* __restrict__ tab) {
  const int lane = threadIdx.x & 63;
  const int row  = blockIdx.x * 4 + (threadIdx.x >> 6);  // (((b*S+s)*3)+which)*16+h
  const int h = row & 15;
  int t = row >> 4;
  const int which = t % 3; t /= 3;
  const int s = t & 2047;
  const int b = t >> 11;
  const size_t src = ((size_t)(b * 2048 + s)) * 6144 + which * 2048 + h * 128 + lane * 2;
  ushort2 xv = *(const ushort2*)&qkv[src];
  if (which == 2) {
    size_t vbase = ((size_t)((b * 16 + h) * 128 + lane * 2)) * 2048 + s;
    vt[vbase]        = xv.x;
    vt[vbase + 2048] = xv.y;
    return;
  }
  float lo = bf2f(xv.x), ro = bf2f(xv.y);
  const float2 cs = *(const float2*)&tab[(s * 64 + lane) * 2];
  float l2 = lo * cs.x - ro * cs.y;
  float r2 = lo * cs.y + ro * cs.x;
  float ss = l2 * l2 + r2 * r2;
#pragma unroll
  for (int off = 1; off < 64; off <<= 1) ss += __shfl_xor(ss, off);
  float inv = rsqrtf(ss * (1.0f / 128.0f) + 1.1920928955078125e-07f);
  if (which == 0) inv *= 0.1275174398f;  // (1/sqrt(128)) * log2(e)
  lo = l2 * inv; ro = r2 * inv;
  ushort_t* dst = (which == 0) ? q : k;
  ushort2 o; o.x = f2bf(lo); o.y = f2bf(ro);
  *(ushort2*)&dst[(((size_t)(b * 16 + h)) * 2048 + s) * 128 + lane * 2] = o;
}

// ---------------------------------------------------------------- flash attention (causal)
__global__ __launch_bounds__(256) void attn_kernel(
    const ushort_t* __restrict__ Q, const ushort_t* __restrict__ K,
    const ushort_t* __restrict__ VT, ushort_t* __restrict__ Y) {
  __shared__ __align__(16) ushort_t sK[64 * 128];
  __shared__ __align__(16) ushort_t sV[128 * 64];
  const int bh = blockIdx.x;
  const int yp = blockIdx.y;
  const int wave = threadIdx.x >> 6, lane = threadIdx.x & 63;
  const int ql = lane & 15, lk = lane >> 4;
  const size_t hq = (size_t)bh * 2048 * 128;
  const int b = bh >> 4, h = bh & 15;

  const char* kB = (const char*)(K + hq);
  const char* vB = (const char*)(VT + hq);
  const char* kSrc[4]; char* kDst[4];
  const char* vSrc[4]; char* vDst[4];
#pragma unroll
  for (int t = 0; t < 4; ++t) {
    int r = wave * 16 + t * 4 + (lane >> 4);
    int kgr = r >> 4, lkr = (r >> 2) & 3, ir = r & 3;
    int rho = (kgr >> 1) * 32 + lkr * 8 + (kgr & 1) * 4 + ir;   // key-permutation
    kSrc[t] = kB + rho * 256 + (((lane & 15) * 16) ^ ((r & 7) << 4));
    kDst[t] = (char*)sK + (wave * 256 + t * 64 + lane) * 16;
    int d = wave * 32 + t * 8 + (lane >> 3);
    vSrc[t] = vB + (size_t)d * 4096 + (((lane & 7) * 16) ^ ((d & 7) << 4));
    vDst[t] = (char*)sV + (wave * 256 + t * 64 + lane) * 16;
  }

  for (int pass = 0; pass < 2; ++pass) {
    const int qt = pass ? (31 - yp) : yp;
    const int q = qt * 64 + wave * 16 + ql;

    bf16x8 qf[4];
#pragma unroll
    for (int ks = 0; ks < 4; ++ks)
      qf[ks] = *(const bf16x8*)&Q[hq + (size_t)q * 128 + ks * 32 + lk * 8];

    f32x4 acc[8];
#pragma unroll
    for (int g = 0; g < 8; ++g) acc[g] = (f32x4){0.f, 0.f, 0.f, 0.f};
    float mrow = -3.0e38f, lsum = 0.f;

    for (int kt = 0; kt <= qt; ++kt) {
#pragma unroll
      for (int t = 0; t < 4; ++t) {
        load_lds16(kSrc[t] + (size_t)kt * 16384, kDst[t]);
        load_lds16(vSrc[t] + kt * 128, vDst[t]);
      }
      __syncthreads();

      // S^T = K . Q^T   (lane&15 = q-row; keys permuted by rho)
      f32x4 st[4];
#pragma unroll
      for (int kg = 0; kg < 4; ++kg) st[kg] = (f32x4){0.f, 0.f, 0.f, 0.f};
#pragma unroll
      for (int kg = 0; kg < 4; ++kg) {
        const int row = kg * 16 + ql;
        const int rswz = (row & 7) << 4;
#pragma unroll
        for (int ks = 0; ks < 4; ++ks) {
          bf16x8 kf = *(const bf16x8*)((const char*)sK + row * 256 + ((ks * 64 + lk * 16) ^ rswz));
          st[kg] = __builtin_amdgcn_mfma_f32_16x16x32_bf16(kf, qf[ks], st[kg], 0, 0, 0);
        }
      }
      float sv[4][4]; float mp = -3.0e38f;
#pragma unroll
      for (int kg = 0; kg < 4; ++kg) {
        const int kl = ((kg >> 1) << 5) + lk * 8 + ((kg & 1) << 2);
#pragma unroll
        for (int i = 0; i < 4; ++i) {
          const int key = kt * 64 + kl + i;
          float v = (key <= q) ? st[kg][i] : -3.0e38f;
          sv[kg][i] = v;
          mp = fmaxf(mp, v);
        }
      }
      mp = fmaxf(mp, __shfl_xor(mp, 16));
      mp = fmaxf(mp, __shfl_xor(mp, 32));
      const float mn = fmaxf(mrow, mp);
      const float corr = exp2f(mrow - mn);
      mrow = mn;
      float p[4][4]; float rs = 0.f;
#pragma unroll
      for (int kg = 0; kg < 4; ++kg)
#pragma unroll
        for (int i = 0; i < 4; ++i) {
          float e = exp2f(sv[kg][i] - mn);
          p[kg][i] = e; rs += e;
        }
      rs += __shfl_xor(rs, 16);
      rs += __shfl_xor(rs, 32);
      lsum = lsum * corr + rs;
#pragma unroll
      for (int g = 0; g < 8; ++g)
#pragma unroll
        for (int i = 0; i < 4; ++i) acc[g][i] *= corr;
      bf16x8 pb[2];
#pragma unroll
      for (int c = 0; c < 2; ++c) {
        union { bf16x8 v; ushort_t u[8]; } pk;
#pragma unroll
        for (int j = 0; j < 8; ++j) pk.u[j] = f2bf(p[2 * c + (j >> 2)][j & 3]);
        pb[c] = pk.v;
      }
#pragma unroll
      for (int dg = 0; dg < 8; ++dg) {
        const int d = dg * 16 + ql;
        const int dswz = (d & 7) << 4;
#pragma unroll
        for (int c = 0; c < 2; ++c) {
          bf16x8 vf = *(const bf16x8*)((const char*)sV + d * 128 + ((c * 64 + lk * 16) ^ dswz));
          acc[dg] = __builtin_amdgcn_mfma_f32_16x16x32_bf16(vf, pb[c], acc[dg], 0, 0, 0);
        }
      }
      __syncthreads();
    }

    const float inv = 1.0f / lsum;
    const size_t orow = ((size_t)(b * 2048 + q)) * 2048 + h * 128;
#pragma unroll
    for (int dg = 0; dg < 8; ++dg) {
      ushort4 o;
      o.x = f2bf(acc[dg][0] * inv);
      o.y = f2bf(acc[dg][1] * inv);
      o.z = f2bf(acc[dg][2] * inv);
      o.w = f2bf(acc[dg][3] * inv);
      *(ushort4*)&Y[orow + dg * 16 + lk * 4] = o;
    }
  }
}

// ---------------------------------------------------------------- launch
extern "C" void kernel_launch(void* const* d_in, const int* in_sizes, int n_in,
                              void* d_out, int out_size, void* d_ws, size_t ws_size,
                              hipStream_t stream) {
  const float* x     = (const float*)d_in[0];
  const float* wqkv  = (const float*)d_in[1];
  const float* wproj = (const float*)d_in[2];
  float* out = (float*)d_out;
  char* ws = (char*)d_ws;

  ushort_t* x_bf     = (ushort_t*)(ws);                // 16,777,216
  ushort_t* wqkv_bf  = (ushort_t*)(ws + 16777216);     // 25,165,824
  ushort_t* wproj_bf = (ushort_t*)(ws + 41943040);     //  8,388,608
  ushort_t* qkv_bf   = (ushort_t*)(ws + 50331648);     // 50,331,648 (reused as y)
  ushort_t* q_bf     = (ushort_t*)(ws + 100663296);    // 16,777,216
  ushort_t* k_bf     = (ushort_t*)(ws + 117440512);    // 16,777,216
  ushort_t* vt_bf    = (ushort_t*)(ws + 134217728);    // 16,777,216 (B,H,D,S)
  float*    tab      = (float*)(ws + 150994944);       //  1,048,576
  if (ws_size < 152043520u) return;

  cast_kernel<<<8192, 256, 0, stream>>>(x, x_bf, 2097152);
  cast_kernel<<<12288, 256, 0, stream>>>(wqkv, wqkv_bf, 3145728);
  cast_kernel<<<4096, 256, 0, stream>>>(wproj, wproj_bf, 1048576);
  rope_tables_kernel<<<512, 256, 0, stream>>>(tab);

  // qkv = x @ w_qkv^T   (4096 x 6144 x 2048), bf16 out, tile 256x256
  gemm8p<256, 0><<<384, 512, 0, stream>>>(x_bf, wqkv_bf, qkv_bf, 4096, 6144, 2048);

  rope_rms_kernel<<<49152, 256, 0, stream>>>(qkv_bf, q_bf, k_bf, vt_bf, tab);

  attn_kernel<<<dim3(32, 16), 256, 0, stream>>>(q_bf, k_bf, vt_bf, qkv_bf /* y */);

  // out = y @ w_proj^T  (4096 x 2048 x 2048), fp32 out, tile 256x128
  gemm8p<128, 1><<<256, 512, 0, stream>>>(qkv_bf, wproj_bf, out, 4096, 2048, 2048);
}

// Round 4
// 313.601 us; speedup vs baseline: 2.1360x; 1.0135x over previous
//
#include <hip/hip_runtime.h>

typedef unsigned short ushort_t;
using bf16x8 = __attribute__((ext_vector_type(8))) short;
using u16x8  = __attribute__((ext_vector_type(8))) unsigned short;
using f32x4  = __attribute__((ext_vector_type(4))) float;

#define DEV static __device__ __forceinline__

DEV unsigned short f2bf(float f) {
  union { float f; unsigned u; } a; a.f = f;
  unsigned r = a.u + 0x7fffu + ((a.u >> 16) & 1u);
  return (unsigned short)(r >> 16);
}
DEV float bf2f(unsigned short u) {
  union { unsigned u; float f; } a; a.u = ((unsigned)u) << 16;
  return a.f;
}
DEV void load_lds16(const void* g, void* l) {
  __builtin_amdgcn_global_load_lds(
      (const __attribute__((address_space(1))) void*)g,
      (__attribute__((address_space(3))) void*)l, 16, 0, 0);
}

// ---------------------------------------------------------------- casts
__global__ __launch_bounds__(256) void cast_kernel(
    const float* __restrict__ src, ushort_t* __restrict__ dst, int n4) {
  int i = blockIdx.x * 256 + threadIdx.x;
  if (i >= n4) return;
  float4 f = ((const float4*)src)[i];
  ushort4 o;
  o.x = f2bf(f.x); o.y = f2bf(f.y); o.z = f2bf(f.z); o.w = f2bf(f.w);
  ((ushort4*)dst)[i] = o;
}

// ---------------------------------------------------------------- rope tables
__global__ __launch_bounds__(256) void rope_tables_kernel(float* __restrict__ tab) {
  int idx = blockIdx.x * 256 + threadIdx.x;   // < 2048*64
  int s = idx >> 6, i = idx & 63;
  float rate = exp2f(-13.287712379549449f * ((float)(2 * i) * (1.0f / 128.0f)));
  float ang = (float)s * rate;
  tab[idx * 2]     = cosf(ang);
  tab[idx * 2 + 1] = sinf(ang);
}

// ---------------------------------------------------------------- deep-pipelined GEMM
// C = A * B^T.  A[M][K], B[N][K] bf16 row-major.  Tile 256 x BN, 512 threads (8 waves).
// 4 LDS slots of BK=32 sub-tiles, counted vmcnt(2L); A-fragments double-buffered in
// registers so ds_read (next step) overlaps MFMA (current step).
template<int BN, int OUTF32>
__global__ __launch_bounds__(512, 2) void gemm_dp(
    const ushort_t* __restrict__ A, const ushort_t* __restrict__ B,
    void* __restrict__ C, int M, int N, int K) {
  constexpr int WROWS   = (BN == 256) ? 128 : 64;   // rows per wave
  constexpr int MF      = WROWS / 16;               // m-frags per wave (8 or 4)
  constexpr int NF      = 4;                        // n-frags per wave (NSPAN=64)
  constexpr int SLOT_A  = 256 * 32;                 // elems
  constexpr int SLOT_B  = BN * 32;
  constexpr int SLOTB   = (SLOT_A + SLOT_B) * 2;    // bytes per slot
  constexpr int LOADS_B = BN / 128;                 // 2 or 1
  __shared__ __align__(16) ushort_t lds[4 * (SLOT_A + SLOT_B)];

  // bijective chunked XCD swizzle (grid % 8 == 0 by construction)
  const int nby = M >> 8;
  const int nwg = nby * (N / BN);
  const int orig = blockIdx.x;
  const int wgid = (orig & 7) * (nwg >> 3) + (orig >> 3);
  const int bm = (wgid % nby) * 256;
  const int bn = (wgid / nby) * BN;

  const int tid = threadIdx.x;
  const int wave = tid >> 6, lane = tid & 63;
  const int ql = lane & 15, lk = lane >> 4;
  const int wm = (BN == 256) ? (wave >> 2) : (wave >> 1);
  const int wn = (BN == 256) ? (wave & 3) : (wave & 1);

  f32x4 acc[MF][NF];
#pragma unroll
  for (int m = 0; m < MF; ++m)
#pragma unroll
    for (int n = 0; n < NF; ++n) acc[m][n] = (f32x4){0.f, 0.f, 0.f, 0.f};

  // ---- staging geometry (source pre-swizzled, LDS dest linear)
  const int srow = tid >> 2;                 // 0..127
  const int sswz = ((tid & 3) * 16) ^ (((srow >> 1) & 3) << 4);
  const size_t rbA = (size_t)(K * 2);
  const char* aS0 = (const char*)A + (size_t)(bm + srow) * rbA + sswz;
  const char* aS1 = (const char*)A + (size_t)(bm + srow + 128) * rbA + sswz;
  const char* bS0 = (const char*)B + (size_t)(bn + srow) * rbA + sswz;
  const char* bS1 = (LOADS_B == 2)
      ? (const char*)B + (size_t)(bn + srow + 128) * rbA + sswz : bS0;
  char* ldsc = (char*)lds;
  const int dA0 = tid * 16;
  const int dA1 = tid * 16 + 8192;
  const int dB0 = SLOT_A * 2 + tid * 16;
  const int dB1 = SLOT_A * 2 + tid * 16 + 8192;

  // ---- fragment read geometry
  const int fcol = (lk * 16) ^ (((ql >> 1) & 3) << 4);
  const int aOff = (wm * WROWS + ql) * 64 + fcol;            // bytes within slot
  const int bOff = SLOT_A * 2 + (wn * 64 + ql) * 64 + fcol;

  const int ns = K >> 5;

#define STEP(S, CUR, NXT) do {                                                  \
    int kn_ = (S) + 3; if (kn_ > ns - 1) kn_ = ns - 1;                          \
    const size_t ko_ = (size_t)kn_ * 64;                                        \
    char* sb_ = ldsc + (((S) + 3) & 3) * SLOTB;                                 \
    load_lds16(aS0 + ko_, sb_ + dA0);                                           \
    load_lds16(aS1 + ko_, sb_ + dA1);                                           \
    load_lds16(bS0 + ko_, sb_ + dB0);                                           \
    if (LOADS_B == 2) load_lds16(bS1 + ko_, sb_ + dB1);                         \
    asm volatile("s_waitcnt vmcnt(%0)" :: "n"(2 * (2 + LOADS_B)) : "memory");   \
    __builtin_amdgcn_s_barrier();                                               \
    asm volatile("" ::: "memory");                                              \
    const char* sbc_ = ldsc + ((S) & 3) * SLOTB;                                \
    const char* sbn_ = ldsc + (((S) + 1) & 3) * SLOTB;                          \
    bf16x8 bfr_[NF];                                                            \
    _Pragma("unroll")                                                           \
    for (int n = 0; n < NF; ++n)                                                \
      bfr_[n] = *(const bf16x8*)(sbc_ + bOff + n * 1024);                       \
    _Pragma("unroll")                                                           \
    for (int m = 0; m < MF; ++m)                                                \
      NXT[m] = *(const bf16x8*)(sbn_ + aOff + m * 1024);                        \
    __builtin_amdgcn_s_setprio(1);                                              \
    _Pragma("unroll")                                                           \
    for (int n = 0; n < NF; ++n)                                                \
      _Pragma("unroll")                                                         \
      for (int m = 0; m < MF; ++m)                                              \
        acc[m][n] = __builtin_amdgcn_mfma_f32_16x16x32_bf16(CUR[m], bfr_[n],    \
                                                            acc[m][n], 0, 0, 0);\
    __builtin_amdgcn_s_setprio(0);                                              \
    __builtin_amdgcn_s_barrier();                                               \
  } while (0)

  // prologue: stage slots 0..2, wait slot 0, read first A-frags
#pragma unroll
  for (int i = 0; i < 3; ++i) {
    const size_t ko = (size_t)i * 64;
    char* sb = ldsc + i * SLOTB;
    load_lds16(aS0 + ko, sb + dA0);
    load_lds16(aS1 + ko, sb + dA1);
    load_lds16(bS0 + ko, sb + dB0);
    if (LOADS_B == 2) load_lds16(bS1 + ko, sb + dB1);
  }
  asm volatile("s_waitcnt vmcnt(%0)" :: "n"(2 * (2 + LOADS_B)) : "memory");
  __builtin_amdgcn_s_barrier();
  asm volatile("" ::: "memory");
  bf16x8 frA[MF], frB[MF];
#pragma unroll
  for (int m = 0; m < MF; ++m) frA[m] = *(const bf16x8*)(ldsc + aOff + m * 1024);

  for (int s = 0; s < ns; s += 2) {
    STEP(s, frA, frB);
    STEP(s + 1, frB, frA);
  }
  asm volatile("s_waitcnt vmcnt(0)" ::: "memory");
#undef STEP

#pragma unroll
  for (int m = 0; m < MF; ++m)
#pragma unroll
    for (int i = 0; i < 4; ++i) {
      const size_t row = (size_t)(bm + wm * WROWS + m * 16 + lk * 4 + i);
#pragma unroll
      for (int n = 0; n < NF; ++n) {
        const size_t col = (size_t)(bn + wn * 64 + n * 16 + ql);
        float v = acc[m][n][i];
        if (OUTF32) ((float*)C)[row * (size_t)N + col] = v;
        else        ((ushort_t*)C)[row * (size_t)N + col] = f2bf(v);
      }
    }
}

// ---------------------------------------------------------------- RoPE + RMS + relayout
// qkv (B,S,3E) bf16 -> q,k (B,H,S,D) bf16 (rope+rms, scale*log2e folded into q);
// v -> vt (B,H,D,S) bf16 (transposed scatter, no transform).
__global__ __launch_bounds__(256) void rope_rms_kernel(
    const ushort_t* __restrict__ qkv, ushort_t* __restrict__ q,
    ushort_t* __restrict__ k, ushort_t* __restrict__ vt,
    const float* __restrict__ tab) {
  const int lane = threadIdx.x & 63;
  const int row  = blockIdx.x * 4 + (threadIdx.x >> 6);  // (((b*S+s)*3)+which)*16+h
  const int h = row & 15;
  int t = row >> 4;
  const int which = t % 3; t /= 3;
  const int s = t & 2047;
  const int b = t >> 11;
  const size_t src = ((size_t)(b * 2048 + s)) * 6144 + which * 2048 + h * 128 + lane * 2;
  ushort2 xv = *(const ushort2*)&qkv[src];
  if (which == 2) {
    size_t vbase = ((size_t)((b * 16 + h) * 128 + lane * 2)) * 2048 + s;
    vt[vbase]        = xv.x;
    vt[vbase + 2048] = xv.y;
    return;
  }
  float lo = bf2f(xv.x), ro = bf2f(xv.y);
  const float2 cs = *(const float2*)&tab[(s * 64 + lane) * 2];
  float l2 = lo * cs.x - ro * cs.y;
  float r2 = lo * cs.y + ro * cs.x;
  float ss = l2 * l2 + r2 * r2;
#pragma unroll
  for (int off = 1; off < 64; off <<= 1) ss += __shfl_xor(ss, off);
  float inv = rsqrtf(ss * (1.0f / 128.0f) + 1.1920928955078125e-07f);
  if (which == 0) inv *= 0.1275174398f;  // (1/sqrt(128)) * log2(e)
  lo = l2 * inv; ro = r2 * inv;
  ushort_t* dst = (which == 0) ? q : k;
  ushort2 o; o.x = f2bf(lo); o.y = f2bf(ro);
  *(ushort2*)&dst[(((size_t)(b * 16 + h)) * 2048 + s) * 128 + lane * 2] = o;
}

// ---------------------------------------------------------------- flash attention (causal)
__global__ __launch_bounds__(256) void attn_kernel(
    const ushort_t* __restrict__ Q, const ushort_t* __restrict__ K,
    const ushort_t* __restrict__ VT, ushort_t* __restrict__ Y) {
  __shared__ __align__(16) ushort_t sK[64 * 128];
  __shared__ __align__(16) ushort_t sV[128 * 64];
  const int bh = blockIdx.x;
  const int yp = blockIdx.y;
  const int wave = threadIdx.x >> 6, lane = threadIdx.x & 63;
  const int ql = lane & 15, lk = lane >> 4;
  const size_t hq = (size_t)bh * 2048 * 128;
  const int b = bh >> 4, h = bh & 15;

  const char* kB = (const char*)(K + hq);
  const char* vB = (const char*)(VT + hq);
  const char* kSrc[4]; char* kDst[4];
  const char* vSrc[4]; char* vDst[4];
#pragma unroll
  for (int t = 0; t < 4; ++t) {
    int r = wave * 16 + t * 4 + (lane >> 4);
    int kgr = r >> 4, lkr = (r >> 2) & 3, ir = r & 3;
    int rho = (kgr >> 1) * 32 + lkr * 8 + (kgr & 1) * 4 + ir;   // key-permutation
    kSrc[t] = kB + rho * 256 + (((lane & 15) * 16) ^ ((r & 7) << 4));
    kDst[t] = (char*)sK + (wave * 256 + t * 64 + lane) * 16;
    int d = wave * 32 + t * 8 + (lane >> 3);
    vSrc[t] = vB + (size_t)d * 4096 + (((lane & 7) * 16) ^ ((d & 7) << 4));
    vDst[t] = (char*)sV + (wave * 256 + t * 64 + lane) * 16;
  }

  for (int pass = 0; pass < 2; ++pass) {
    const int qt = pass ? (31 - yp) : yp;
    const int q = qt * 64 + wave * 16 + ql;

    bf16x8 qf[4];
#pragma unroll
    for (int ks = 0; ks < 4; ++ks)
      qf[ks] = *(const bf16x8*)&Q[hq + (size_t)q * 128 + ks * 32 + lk * 8];

    f32x4 acc[8];
#pragma unroll
    for (int g = 0; g < 8; ++g) acc[g] = (f32x4){0.f, 0.f, 0.f, 0.f};
    float mrow = -3.0e38f, lsum = 0.f;

    for (int kt = 0; kt <= qt; ++kt) {
#pragma unroll
      for (int t = 0; t < 4; ++t) {
        load_lds16(kSrc[t] + (size_t)kt * 16384, kDst[t]);
        load_lds16(vSrc[t] + kt * 128, vDst[t]);
      }
      __syncthreads();

      // S^T = K . Q^T   (lane&15 = q-row; keys permuted by rho)
      f32x4 st[4];
#pragma unroll
      for (int kg = 0; kg < 4; ++kg) st[kg] = (f32x4){0.f, 0.f, 0.f, 0.f};
#pragma unroll
      for (int kg = 0; kg < 4; ++kg) {
        const int row = kg * 16 + ql;
        const int rswz = (row & 7) << 4;
#pragma unroll
        for (int ks = 0; ks < 4; ++ks) {
          bf16x8 kf = *(const bf16x8*)((const char*)sK + row * 256 + ((ks * 64 + lk * 16) ^ rswz));
          st[kg] = __builtin_amdgcn_mfma_f32_16x16x32_bf16(kf, qf[ks], st[kg], 0, 0, 0);
        }
      }
      float sv[4][4]; float mp = -3.0e38f;
#pragma unroll
      for (int kg = 0; kg < 4; ++kg) {
        const int kl = ((kg >> 1) << 5) + lk * 8 + ((kg & 1) << 2);
#pragma unroll
        for (int i = 0; i < 4; ++i) {
          const int key = kt * 64 + kl + i;
          float v = (key <= q) ? st[kg][i] : -3.0e38f;
          sv[kg][i] = v;
          mp = fmaxf(mp, v);
        }
      }
      mp = fmaxf(mp, __shfl_xor(mp, 16));
      mp = fmaxf(mp, __shfl_xor(mp, 32));
      const float mn = fmaxf(mrow, mp);
      const float corr = exp2f(mrow - mn);
      mrow = mn;
      float p[4][4]; float rs = 0.f;
#pragma unroll
      for (int kg = 0; kg < 4; ++kg)
#pragma unroll
        for (int i = 0; i < 4; ++i) {
          float e = exp2f(sv[kg][i] - mn);
          p[kg][i] = e; rs += e;
        }
      rs += __shfl_xor(rs, 16);
      rs += __shfl_xor(rs, 32);
      lsum = lsum * corr + rs;
#pragma unroll
      for (int g = 0; g < 8; ++g)
#pragma unroll
        for (int i = 0; i < 4; ++i) acc[g][i] *= corr;
      bf16x8 pb[2];
#pragma unroll
      for (int c = 0; c < 2; ++c) {
        union { bf16x8 v; ushort_t u[8]; } pk;
#pragma unroll
        for (int j = 0; j < 8; ++j) pk.u[j] = f2bf(p[2 * c + (j >> 2)][j & 3]);
        pb[c] = pk.v;
      }
#pragma unroll
      for (int dg = 0; dg < 8; ++dg) {
        const int d = dg * 16 + ql;
        const int dswz = (d & 7) << 4;
#pragma unroll
        for (int c = 0; c < 2; ++c) {
          bf16x8 vf = *(const bf16x8*)((const char*)sV + d * 128 + ((c * 64 + lk * 16) ^ dswz));
          acc[dg] = __builtin_amdgcn_mfma_f32_16x16x32_bf16(vf, pb[c], acc[dg], 0, 0, 0);
        }
      }
      __syncthreads();
    }

    const float inv = 1.0f / lsum;
    const size_t orow = ((size_t)(b * 2048 + q)) * 2048 + h * 128;
#pragma unroll
    for (int dg = 0; dg < 8; ++dg) {
      ushort4 o;
      o.x = f2bf(acc[dg][0] * inv);
      o.y = f2bf(acc[dg][1] * inv);
      o.z = f2bf(acc[dg][2] * inv);
      o.w = f2bf(acc[dg][3] * inv);
      *(ushort4*)&Y[orow + dg * 16 + lk * 4] = o;
    }
  }
}

// ---------------------------------------------------------------- launch
extern "C" void kernel_launch(void* const* d_in, const int* in_sizes, int n_in,
                              void* d_out, int out_size, void* d_ws, size_t ws_size,
                              hipStream_t stream) {
  const float* x     = (const float*)d_in[0];
  const float* wqkv  = (const float*)d_in[1];
  const float* wproj = (const float*)d_in[2];
  float* out = (float*)d_out;
  char* ws = (char*)d_ws;

  ushort_t* x_bf     = (ushort_t*)(ws);                // 16,777,216
  ushort_t* wqkv_bf  = (ushort_t*)(ws + 16777216);     // 25,165,824
  ushort_t* wproj_bf = (ushort_t*)(ws + 41943040);     //  8,388,608
  ushort_t* qkv_bf   = (ushort_t*)(ws + 50331648);     // 50,331,648 (reused as y)
  ushort_t* q_bf     = (ushort_t*)(ws + 100663296);    // 16,777,216
  ushort_t* k_bf     = (ushort_t*)(ws + 117440512);    // 16,777,216
  ushort_t* vt_bf    = (ushort_t*)(ws + 134217728);    // 16,777,216 (B,H,D,S)
  float*    tab      = (float*)(ws + 150994944);       //  1,048,576
  if (ws_size < 152043520u) return;

  cast_kernel<<<8192, 256, 0, stream>>>(x, x_bf, 2097152);
  cast_kernel<<<12288, 256, 0, stream>>>(wqkv, wqkv_bf, 3145728);
  cast_kernel<<<4096, 256, 0, stream>>>(wproj, wproj_bf, 1048576);
  rope_tables_kernel<<<512, 256, 0, stream>>>(tab);

  // qkv = x @ w_qkv^T   (4096 x 6144 x 2048), bf16 out, tile 256x256
  gemm_dp<256, 0><<<384, 512, 0, stream>>>(x_bf, wqkv_bf, qkv_bf, 4096, 6144, 2048);

  rope_rms_kernel<<<49152, 256, 0, stream>>>(qkv_bf, q_bf, k_bf, vt_bf, tab);

  attn_kernel<<<dim3(32, 16), 256, 0, stream>>>(q_bf, k_bf, vt_bf, qkv_bf /* y */);

  // out = y @ w_proj^T  (4096 x 2048 x 2048), fp32 out, tile 256x128
  gemm_dp<128, 1><<<256, 512, 0, stream>>>(qkv_bf, wproj_bf, out, 4096, 2048, 2048);
}

// Round 5
// 307.792 us; speedup vs baseline: 2.1763x; 1.0189x over previous
//
#include <hip/hip_runtime.h>

typedef unsigned short ushort_t;
using bf16x8 = __attribute__((ext_vector_type(8))) short;
using u16x8  = __attribute__((ext_vector_type(8))) unsigned short;
using f32x4  = __attribute__((ext_vector_type(4))) float;

#define DEV static __device__ __forceinline__

DEV unsigned short f2bf(float f) {
  union { float f; unsigned u; } a; a.f = f;
  unsigned r = a.u + 0x7fffu + ((a.u >> 16) & 1u);
  return (unsigned short)(r >> 16);
}
DEV float bf2f(unsigned short u) {
  union { unsigned u; float f; } a; a.u = ((unsigned)u) << 16;
  return a.f;
}
DEV void load_lds16(const void* g, void* l) {
  __builtin_amdgcn_global_load_lds(
      (const __attribute__((address_space(1))) void*)g,
      (__attribute__((address_space(3))) void*)l, 16, 0, 0);
}
DEV bf16x8 mfma16(bf16x8 a, bf16x8 b);  // fwd decl not needed; use builtin inline

// ---------------------------------------------------------------- casts
__global__ __launch_bounds__(256) void cast_kernel(
    const float* __restrict__ src, ushort_t* __restrict__ dst, int n4) {
  int i = blockIdx.x * 256 + threadIdx.x;
  if (i >= n4) return;
  float4 f = ((const float4*)src)[i];
  ushort4 o;
  o.x = f2bf(f.x); o.y = f2bf(f.y); o.z = f2bf(f.z); o.w = f2bf(f.w);
  ((ushort4*)dst)[i] = o;
}

// ---------------------------------------------------------------- rope tables
__global__ __launch_bounds__(256) void rope_tables_kernel(float* __restrict__ tab) {
  int idx = blockIdx.x * 256 + threadIdx.x;   // < 2048*64
  int s = idx >> 6, i = idx & 63;
  float rate = exp2f(-13.287712379549449f * ((float)(2 * i) * (1.0f / 128.0f)));
  float ang = (float)s * rate;
  tab[idx * 2]     = cosf(ang);
  tab[idx * 2 + 1] = sinf(ang);
}

// ---------------------------------------------------------------- 8-phase GEMM
// C = A * B^T. A[M][K], B[N][K] bf16 row-major. Tile 256 x BN, BK=64, 512 threads
// (8 waves: 2M x 4N). Double-buffered K-tiles; 4 phases per K-tile, each
// {ds_read quadrant frags, stage chunks, barrier, 16(8) MFMA, barrier};
// counted vmcnt only (6/2 per K-tile), every staged chunk gets >=3 phases in flight.
// LDS swizzle: 16B-slot XOR (row&7), applied on pre-swizzled global source + reads.
template<int BN, int OUTF32>
__global__ __launch_bounds__(512, 2) void gemm8(
    const ushort_t* __restrict__ A, const ushort_t* __restrict__ Bm,
    void* __restrict__ C, int M, int N, int K) {
  constexpr int NF   = BN / 64;          // n-frags per wave: 4 or 2
  constexpr int ABY  = 256 * 64 * 2;     // A K-tile bytes (32768)
  constexpr int BBY  = BN * 64 * 2;      // B K-tile bytes
  constexpr int BUFB = ABY + BBY;
  __shared__ __align__(16) char lds[2 * BUFB];

  // bijective chunked XCD swizzle (grid % 8 == 0 by construction)
  const int nby = M >> 8;
  const int nwg = nby * (N / BN);
  const int orig = blockIdx.x;
  const int wgid = (orig & 7) * (nwg >> 3) + (orig >> 3);
  const int bm = (wgid % nby) * 256;
  const int bn = (wgid / nby) * BN;

  const int tid = threadIdx.x;
  const int lane = tid & 63;
  const int wave = tid >> 6;
  const int ql = lane & 15, lk = lane >> 4;
  const int wm = wave >> 2, wn = wave & 3;

  f32x4 acc[8][NF];
#pragma unroll
  for (int m = 0; m < 8; ++m)
#pragma unroll
    for (int n = 0; n < NF; ++n) acc[m][n] = (f32x4){0.f, 0.f, 0.f, 0.f};

  // staging: chunk = 64 rows x 64 k (8 KB) = 1 load/thread; source pre-swizzled
  const int srow = tid >> 3;                       // 0..63 within chunk
  const int scol = ((tid & 7) ^ (srow & 7)) * 16;  // swizzled 16B slot
  const size_t rb = (size_t)K * 2;
  const char* aS[4];
#pragma unroll
  for (int c = 0; c < 4; ++c)
    aS[c] = (const char*)A + (size_t)(bm + c * 64 + srow) * rb + scol;
  const char* bS[NF];
#pragma unroll
  for (int c = 0; c < NF; ++c)
    bS[c] = (const char*)Bm + (size_t)(bn + c * 64 + srow) * rb + scol;
  char* const ldsc = (char*)lds;
  const int dT = tid * 16;

  // fragment read geometry (row*128 + (slot ^ (row&7))*16 ; row&7 == ql&7)
  const int aRow = wm * 128 + ql;
  const int bRow = wn * (BN / 4) + ql;
  const int qx = ql & 7;

#define RDA(BUF, m, kh) \
  (*(const bf16x8*)((BUF) + (aRow + (m) * 16) * 128 + ((((kh) << 2) | lk) ^ qx) * 16))
#define RDB(BUF, n, kh) \
  (*(const bf16x8*)((BUF) + ABY + (bRow + (n) * 16) * 128 + ((((kh) << 2) | lk) ^ qx) * 16))
#define STGA(BUF, KT, c) load_lds16(aS[c] + (size_t)(KT) * 128, (BUF) + (c) * 8192 + dT)
#define STGB(BUF, KT, c) load_lds16(bS[c] + (size_t)(KT) * 128, (BUF) + ABY + (c) * 8192 + dT)
#define MFMA(a, b, c) __builtin_amdgcn_mfma_f32_16x16x32_bf16(a, b, c, 0, 0, 0)

  const int ns = K >> 6;   // K-tiles

  // prologue: stage t0 (early chunks first), allow late A-halves outstanding
  STGA(ldsc, 0, 0); STGA(ldsc, 0, 2);
  STGB(ldsc, 0, 0); STGB(ldsc, 0, 1);
  if constexpr (NF == 4) { STGB(ldsc, 0, 2); STGB(ldsc, 0, 3); }
  STGA(ldsc, 0, 1); STGA(ldsc, 0, 3);
  asm volatile("s_waitcnt vmcnt(2)" ::: "memory");
  __builtin_amdgcn_s_barrier();

  for (int t = 0; t < ns; ++t) {
    char* bufR = ldsc + (t & 1) * BUFB;
    char* bufW = ldsc + ((t + 1) & 1) * BUFB;
    const int kn = (t + 1 < ns) ? t + 1 : ns - 1;  // clamped dummy keeps counts uniform

    if constexpr (NF == 4) {
      bf16x8 aF[4][2], bF[4][2];
      // ---- P0: quadrant (m0-3, n0-1)
#pragma unroll
      for (int mi = 0; mi < 4; ++mi) {
        aF[mi][0] = RDA(bufR, mi, 0); aF[mi][1] = RDA(bufR, mi, 1);
      }
#pragma unroll
      for (int n = 0; n < 2; ++n) {
        bF[n][0] = RDB(bufR, n, 0); bF[n][1] = RDB(bufR, n, 1);
      }
      STGA(bufW, kn, 0); STGA(bufW, kn, 2);
      STGB(bufW, kn, 0); STGB(bufW, kn, 1); STGB(bufW, kn, 2); STGB(bufW, kn, 3);
      __builtin_amdgcn_s_barrier();
      __builtin_amdgcn_s_setprio(1);
#pragma unroll
      for (int n = 0; n < 2; ++n)
#pragma unroll
        for (int kh = 0; kh < 2; ++kh)
#pragma unroll
          for (int mi = 0; mi < 4; ++mi)
            acc[mi][n] = MFMA(aF[mi][kh], bF[n][kh], acc[mi][n]);
      __builtin_amdgcn_s_setprio(0);
      __builtin_amdgcn_s_barrier();
      // ---- P1: quadrant (m0-3, n2-3)
#pragma unroll
      for (int n = 2; n < 4; ++n) {
        bF[n][0] = RDB(bufR, n, 0); bF[n][1] = RDB(bufR, n, 1);
      }
      asm volatile("s_waitcnt vmcnt(6)" ::: "memory");
      __builtin_amdgcn_s_barrier();
      __builtin_amdgcn_s_setprio(1);
#pragma unroll
      for (int n = 2; n < 4; ++n)
#pragma unroll
        for (int kh = 0; kh < 2; ++kh)
#pragma unroll
          for (int mi = 0; mi < 4; ++mi)
            acc[mi][n] = MFMA(aF[mi][kh], bF[n][kh], acc[mi][n]);
      __builtin_amdgcn_s_setprio(0);
      __builtin_amdgcn_s_barrier();
      // ---- P2: quadrant (m4-7, n0-1)
#pragma unroll
      for (int mi = 0; mi < 4; ++mi) {
        aF[mi][0] = RDA(bufR, 4 + mi, 0); aF[mi][1] = RDA(bufR, 4 + mi, 1);
      }
      STGA(bufW, kn, 1); STGA(bufW, kn, 3);
      __builtin_amdgcn_s_barrier();
      __builtin_amdgcn_s_setprio(1);
#pragma unroll
      for (int n = 0; n < 2; ++n)
#pragma unroll
        for (int kh = 0; kh < 2; ++kh)
#pragma unroll
          for (int mi = 0; mi < 4; ++mi)
            acc[4 + mi][n] = MFMA(aF[mi][kh], bF[n][kh], acc[4 + mi][n]);
      __builtin_amdgcn_s_setprio(0);
      __builtin_amdgcn_s_barrier();
      // ---- P3: quadrant (m4-7, n2-3), MFMA-only
      __builtin_amdgcn_s_setprio(1);
#pragma unroll
      for (int n = 2; n < 4; ++n)
#pragma unroll
        for (int kh = 0; kh < 2; ++kh)
#pragma unroll
          for (int mi = 0; mi < 4; ++mi)
            acc[4 + mi][n] = MFMA(aF[mi][kh], bF[n][kh], acc[4 + mi][n]);
      __builtin_amdgcn_s_setprio(0);
      asm volatile("s_waitcnt vmcnt(2)" ::: "memory");
      __builtin_amdgcn_s_barrier();
    } else {
      bf16x8 aF0[4], aF1[4], bF[2][2];
      // ---- P0: (m0-3, k0)
#pragma unroll
      for (int mi = 0; mi < 4; ++mi) aF0[mi] = RDA(bufR, mi, 0);
      bF[0][0] = RDB(bufR, 0, 0); bF[1][0] = RDB(bufR, 1, 0);
      STGA(bufW, kn, 0); STGA(bufW, kn, 2);
      STGB(bufW, kn, 0); STGB(bufW, kn, 1);
      __builtin_amdgcn_s_barrier();
      __builtin_amdgcn_s_setprio(1);
#pragma unroll
      for (int n = 0; n < 2; ++n)
#pragma unroll
        for (int mi = 0; mi < 4; ++mi)
          acc[mi][n] = MFMA(aF0[mi], bF[n][0], acc[mi][n]);
      __builtin_amdgcn_s_setprio(0);
      __builtin_amdgcn_s_barrier();
      // ---- P1: (m0-3, k1)
#pragma unroll
      for (int mi = 0; mi < 4; ++mi) aF1[mi] = RDA(bufR, mi, 1);
      bF[0][1] = RDB(bufR, 0, 1); bF[1][1] = RDB(bufR, 1, 1);
      asm volatile("s_waitcnt vmcnt(4)" ::: "memory");
      __builtin_amdgcn_s_barrier();
      __builtin_amdgcn_s_setprio(1);
#pragma unroll
      for (int n = 0; n < 2; ++n)
#pragma unroll
        for (int mi = 0; mi < 4; ++mi)
          acc[mi][n] = MFMA(aF1[mi], bF[n][1], acc[mi][n]);
      __builtin_amdgcn_s_setprio(0);
      __builtin_amdgcn_s_barrier();
      // ---- P2: (m4-7, k0)
#pragma unroll
      for (int mi = 0; mi < 4; ++mi) aF0[mi] = RDA(bufR, 4 + mi, 0);
      STGA(bufW, kn, 1); STGA(bufW, kn, 3);
      __builtin_amdgcn_s_barrier();
      __builtin_amdgcn_s_setprio(1);
#pragma unroll
      for (int n = 0; n < 2; ++n)
#pragma unroll
        for (int mi = 0; mi < 4; ++mi)
          acc[4 + mi][n] = MFMA(aF0[mi], bF[n][0], acc[4 + mi][n]);
      __builtin_amdgcn_s_setprio(0);
      __builtin_amdgcn_s_barrier();
      // ---- P3: (m4-7, k1)
#pragma unroll
      for (int mi = 0; mi < 4; ++mi) aF1[mi] = RDA(bufR, 4 + mi, 1);
      __builtin_amdgcn_s_barrier();
      __builtin_amdgcn_s_setprio(1);
#pragma unroll
      for (int n = 0; n < 2; ++n)
#pragma unroll
        for (int mi = 0; mi < 4; ++mi)
          acc[4 + mi][n] = MFMA(aF1[mi], bF[n][1], acc[4 + mi][n]);
      __builtin_amdgcn_s_setprio(0);
      asm volatile("s_waitcnt vmcnt(2)" ::: "memory");
      __builtin_amdgcn_s_barrier();
    }
  }
#undef RDA
#undef RDB
#undef STGA
#undef STGB
#undef MFMA

#pragma unroll
  for (int m = 0; m < 8; ++m)
#pragma unroll
    for (int i = 0; i < 4; ++i) {
      const size_t row = (size_t)(bm + wm * 128 + m * 16 + lk * 4 + i);
#pragma unroll
      for (int n = 0; n < NF; ++n) {
        const size_t col = (size_t)(bn + wn * (BN / 4) + n * 16 + ql);
        float v = acc[m][n][i];
        if (OUTF32) ((float*)C)[row * (size_t)N + col] = v;
        else        ((ushort_t*)C)[row * (size_t)N + col] = f2bf(v);
      }
    }
}

// ---------------------------------------------------------------- RoPE + RMS + relayout
__global__ __launch_bounds__(256) void rope_rms_kernel(
    const ushort_t* __restrict__ qkv, ushort_t* __restrict__ q,
    ushort_t* __restrict__ k, ushort_t* __restrict__ vt,
    const float* __restrict__ tab) {
  const int lane = threadIdx.x & 63;
  const int row  = blockIdx.x * 4 + (threadIdx.x >> 6);  // (((b*S+s)*3)+which)*16+h
  const int h = row & 15;
  int t = row >> 4;
  const int which = t % 3; t /= 3;
  const int s = t & 2047;
  const int b = t >> 11;
  const size_t src = ((size_t)(b * 2048 + s)) * 6144 + which * 2048 + h * 128 + lane * 2;
  ushort2 xv = *(const ushort2*)&qkv[src];
  if (which == 2) {
    size_t vbase = ((size_t)((b * 16 + h) * 128 + lane * 2)) * 2048 + s;
    vt[vbase]        = xv.x;
    vt[vbase + 2048] = xv.y;
    return;
  }
  float lo = bf2f(xv.x), ro = bf2f(xv.y);
  const float2 cs = *(const float2*)&tab[(s * 64 + lane) * 2];
  float l2 = lo * cs.x - ro * cs.y;
  float r2 = lo * cs.y + ro * cs.x;
  float ss = l2 * l2 + r2 * r2;
#pragma unroll
  for (int off = 1; off < 64; off <<= 1) ss += __shfl_xor(ss, off);
  float inv = rsqrtf(ss * (1.0f / 128.0f) + 1.1920928955078125e-07f);
  if (which == 0) inv *= 0.1275174398f;  // (1/sqrt(128)) * log2(e)
  lo = l2 * inv; ro = r2 * inv;
  ushort_t* dst = (which == 0) ? q : k;
  ushort2 o; o.x = f2bf(lo); o.y = f2bf(ro);
  *(ushort2*)&dst[(((size_t)(b * 16 + h)) * 2048 + s) * 128 + lane * 2] = o;
}

// ---------------------------------------------------------------- flash attention (causal)
__global__ __launch_bounds__(256) void attn_kernel(
    const ushort_t* __restrict__ Q, const ushort_t* __restrict__ K,
    const ushort_t* __restrict__ VT, ushort_t* __restrict__ Y) {
  __shared__ __align__(16) ushort_t sK[64 * 128];
  __shared__ __align__(16) ushort_t sV[128 * 64];
  const int bh = blockIdx.x;
  const int yp = blockIdx.y;
  const int wave = threadIdx.x >> 6, lane = threadIdx.x & 63;
  const int ql = lane & 15, lk = lane >> 4;
  const size_t hq = (size_t)bh * 2048 * 128;
  const int b = bh >> 4, h = bh & 15;

  const char* kB = (const char*)(K + hq);
  const char* vB = (const char*)(VT + hq);
  const char* kSrc[4]; char* kDst[4];
  const char* vSrc[4]; char* vDst[4];
#pragma unroll
  for (int t = 0; t < 4; ++t) {
    int r = wave * 16 + t * 4 + (lane >> 4);
    int kgr = r >> 4, lkr = (r >> 2) & 3, ir = r & 3;
    int rho = (kgr >> 1) * 32 + lkr * 8 + (kgr & 1) * 4 + ir;   // key-permutation
    kSrc[t] = kB + rho * 256 + (((lane & 15) * 16) ^ ((r & 7) << 4));
    kDst[t] = (char*)sK + (wave * 256 + t * 64 + lane) * 16;
    int d = wave * 32 + t * 8 + (lane >> 3);
    vSrc[t] = vB + (size_t)d * 4096 + (((lane & 7) * 16) ^ ((d & 7) << 4));
    vDst[t] = (char*)sV + (wave * 256 + t * 64 + lane) * 16;
  }

  for (int pass = 0; pass < 2; ++pass) {
    const int qt = pass ? (31 - yp) : yp;
    const int q = qt * 64 + wave * 16 + ql;

    bf16x8 qf[4];
#pragma unroll
    for (int ks = 0; ks < 4; ++ks)
      qf[ks] = *(const bf16x8*)&Q[hq + (size_t)q * 128 + ks * 32 + lk * 8];

    f32x4 acc[8];
#pragma unroll
    for (int g = 0; g < 8; ++g) acc[g] = (f32x4){0.f, 0.f, 0.f, 0.f};
    float mrow = -3.0e38f, lsum = 0.f;

    for (int kt = 0; kt <= qt; ++kt) {
#pragma unroll
      for (int t = 0; t < 4; ++t) {
        load_lds16(kSrc[t] + (size_t)kt * 16384, kDst[t]);
        load_lds16(vSrc[t] + kt * 128, vDst[t]);
      }
      __syncthreads();

      // S^T = K . Q^T   (lane&15 = q-row; keys permuted by rho)
      f32x4 st[4];
#pragma unroll
      for (int kg = 0; kg < 4; ++kg) st[kg] = (f32x4){0.f, 0.f, 0.f, 0.f};
#pragma unroll
      for (int kg = 0; kg < 4; ++kg) {
        const int row = kg * 16 + ql;
        const int rswz = (row & 7) << 4;
#pragma unroll
        for (int ks = 0; ks < 4; ++ks) {
          bf16x8 kf = *(const bf16x8*)((const char*)sK + row * 256 + ((ks * 64 + lk * 16) ^ rswz));
          st[kg] = __builtin_amdgcn_mfma_f32_16x16x32_bf16(kf, qf[ks], st[kg], 0, 0, 0);
        }
      }
      float sv[4][4]; float mp = -3.0e38f;
#pragma unroll
      for (int kg = 0; kg < 4; ++kg) {
        const int kl = ((kg >> 1) << 5) + lk * 8 + ((kg & 1) << 2);
#pragma unroll
        for (int i = 0; i < 4; ++i) {
          const int key = kt * 64 + kl + i;
          float v = (key <= q) ? st[kg][i] : -3.0e38f;
          sv[kg][i] = v;
          mp = fmaxf(mp, v);
        }
      }
      mp = fmaxf(mp, __shfl_xor(mp, 16));
      mp = fmaxf(mp, __shfl_xor(mp, 32));
      const float mn = fmaxf(mrow, mp);
      const float corr = exp2f(mrow - mn);
      mrow = mn;
      float p[4][4]; float rs = 0.f;
#pragma unroll
      for (int kg = 0; kg < 4; ++kg)
#pragma unroll
        for (int i = 0; i < 4; ++i) {
          float e = exp2f(sv[kg][i] - mn);
          p[kg][i] = e; rs += e;
        }
      rs += __shfl_xor(rs, 16);
      rs += __shfl_xor(rs, 32);
      lsum = lsum * corr + rs;
#pragma unroll
      for (int g = 0; g < 8; ++g)
#pragma unroll
        for (int i = 0; i < 4; ++i) acc[g][i] *= corr;
      bf16x8 pb[2];
#pragma unroll
      for (int c = 0; c < 2; ++c) {
        union { bf16x8 v; ushort_t u[8]; } pk;
#pragma unroll
        for (int j = 0; j < 8; ++j) pk.u[j] = f2bf(p[2 * c + (j >> 2)][j & 3]);
        pb[c] = pk.v;
      }
#pragma unroll
      for (int dg = 0; dg < 8; ++dg) {
        const int d = dg * 16 + ql;
        const int dswz = (d & 7) << 4;
#pragma unroll
        for (int c = 0; c < 2; ++c) {
          bf16x8 vf = *(const bf16x8*)((const char*)sV + d * 128 + ((c * 64 + lk * 16) ^ dswz));
          acc[dg] = __builtin_amdgcn_mfma_f32_16x16x32_bf16(vf, pb[c], acc[dg], 0, 0, 0);
        }
      }
      __syncthreads();
    }

    const float inv = 1.0f / lsum;
    const size_t orow = ((size_t)(b * 2048 + q)) * 2048 + h * 128;
#pragma unroll
    for (int dg = 0; dg < 8; ++dg) {
      ushort4 o;
      o.x = f2bf(acc[dg][0] * inv);
      o.y = f2bf(acc[dg][1] * inv);
      o.z = f2bf(acc[dg][2] * inv);
      o.w = f2bf(acc[dg][3] * inv);
      *(ushort4*)&Y[orow + dg * 16 + lk * 4] = o;
    }
  }
}

// ---------------------------------------------------------------- launch
extern "C" void kernel_launch(void* const* d_in, const int* in_sizes, int n_in,
                              void* d_out, int out_size, void* d_ws, size_t ws_size,
                              hipStream_t stream) {
  const float* x     = (const float*)d_in[0];
  const float* wqkv  = (const float*)d_in[1];
  const float* wproj = (const float*)d_in[2];
  float* out = (float*)d_out;
  char* ws = (char*)d_ws;

  ushort_t* x_bf     = (ushort_t*)(ws);                // 16,777,216
  ushort_t* wqkv_bf  = (ushort_t*)(ws + 16777216);     // 25,165,824
  ushort_t* wproj_bf = (ushort_t*)(ws + 41943040);     //  8,388,608
  ushort_t* qkv_bf   = (ushort_t*)(ws + 50331648);     // 50,331,648 (reused as y)
  ushort_t* q_bf     = (ushort_t*)(ws + 100663296);    // 16,777,216
  ushort_t* k_bf     = (ushort_t*)(ws + 117440512);    // 16,777,216
  ushort_t* vt_bf    = (ushort_t*)(ws + 134217728);    // 16,777,216 (B,H,D,S)
  float*    tab      = (float*)(ws + 150994944);       //  1,048,576
  if (ws_size < 152043520u) return;

  cast_kernel<<<8192, 256, 0, stream>>>(x, x_bf, 2097152);
  cast_kernel<<<12288, 256, 0, stream>>>(wqkv, wqkv_bf, 3145728);
  cast_kernel<<<4096, 256, 0, stream>>>(wproj, wproj_bf, 1048576);
  rope_tables_kernel<<<512, 256, 0, stream>>>(tab);

  // qkv = x @ w_qkv^T   (4096 x 6144 x 2048), bf16 out, tile 256x256
  gemm8<256, 0><<<384, 512, 0, stream>>>(x_bf, wqkv_bf, qkv_bf, 4096, 6144, 2048);

  rope_rms_kernel<<<49152, 256, 0, stream>>>(qkv_bf, q_bf, k_bf, vt_bf, tab);

  attn_kernel<<<dim3(32, 16), 256, 0, stream>>>(q_bf, k_bf, vt_bf, qkv_bf /* y */);

  // out = y @ w_proj^T  (4096 x 2048 x 2048), fp32 out, tile 256x128, grid 256 exact
  gemm8<128, 1><<<256, 512, 0, stream>>>(qkv_bf, wproj_bf, out, 4096, 2048, 2048);
}